// Round 8
// baseline (47.573 us; speedup 1.0000x reference)
//
#include <hip/hip_runtime.h>
#include <math.h>

// ---------------------------------------------------------------------------
// Net: conv2d(3->1,5x5,VALID) + bias -> xor_linear(784->128) -> step ->
//      xor_linear(128->64) -> step -> xor_linear(64->10) -> log_softmax
//
// xor_linear(X,W,b) = popcount(Xbits ^ Wbits) + b - in/2. First layer
// binarizes with (conv+bias != 0) [ref: Xb = (X != 0)], later layers with
// step() (>= 0). Integer-exact -> bit-exact thresholds.
//
// Structure: ONE sample per wave (8192 waves = 8 waves/SIMD). lane =
// rowparity*32 + col; step t processes input rows 2t (lanes 0-31) and
// 2t+1 (lanes 32-63). Column shifts via chained DPP wave_shr:1 (pure
// VALU). A[d] = pending output row at distance d from MY row; rotates by
// 2/step via static renames. Retire: __shfl_xor(.,32) combines halves,
// ballot binarizes, lanes 0..27 collect row masks.
//
// ROUND-8 CHANGE: 8-row register ring buffer (24 VGPR) with a 24-load
// initial burst and 3-issue/3-consume steady state -> ~1700cy of load
// lookahead (vs 2-step=420cy before). The r7 rolled-loop regression
// showed ~10us sensitivity per prefetch step -> per-step vmcnt stall was
// the plateau. Counted vmcnt, never drained. No LDS/barriers/atomics.
// ---------------------------------------------------------------------------

#define NW1P 28   // padded u32 words per W1 row
#define DPP_WAVE_SHR1 0x138
#define W1_BLOCKS 400   // 128 rows * 25 words * 32 bits / 256 threads
#define W2_BLOCKS 32    // 128 u64 words, 4 per block (one ballot per wave)

__global__ void pack_weights(const float* __restrict__ W1,
                             const float* __restrict__ W2,
                             const float* __restrict__ W3,
                             unsigned* __restrict__ w1t,
                             unsigned long long* __restrict__ w2b,
                             unsigned long long* __restrict__ w3b) {
    const int bid = blockIdx.x, t = threadIdx.x;
    const int lane = t & 63, wv = t >> 6;
    if (bid < W1_BLOCKS) {
        // one bit per lane; ballot assembles two u32 words per wave
        int gid = bid * 256 + t;
        int wf  = gid >> 5;                 // flat word index 0..3199
        int bit = gid & 31;
        int i = wf / 25, j = wf - i * 25;   // row i, word j
        int col = j * 32 + bit;
        bool v = (col < 784) && (W1[i * 784 + col] != 0.0f);
        unsigned long long m = __ballot(v);
        if (bit == 0)
            w1t[i * NW1P + j] = (unsigned)(m >> ((t & 32) ? 32 : 0));
    } else if (bid < W1_BLOCKS + W2_BLOCKS) {
        // one u64 word per wave: word f = w*64+i holds W2[i][w*64+lane]
        int f = (bid - W1_BLOCKS) * 4 + wv;       // 0..127
        int w = f >> 6, i = f & 63;
        bool v = W2[i * 128 + w * 64 + lane] != 0.0f;
        unsigned long long m = __ballot(v);
        if (lane == 0) w2b[f] = m;
    } else {
        if (wv == 0) {                             // W3: 10 ballots on wave 0
            #pragma unroll
            for (int f = 0; f < 10; ++f) {
                bool v = W3[f * 64 + lane] != 0.0f;
                unsigned long long m = __ballot(v);
                if (lane == 0) w3b[f] = m;
            }
        } else if (t >= 128 && t < 256) {          // zero w1t pad words
            int i = t - 128;
            w1t[i * NW1P + 25] = 0;
            w1t[i * NW1P + 26] = 0;
            w1t[i * NW1P + 27] = 0;
        }
    }
}

__global__ __launch_bounds__(256, 8) void net_all(
        const float* __restrict__ x,        // (B,3,32,32)
        const float* __restrict__ conv_w,   // (1,3,5,5)
        const float* __restrict__ conv_b,   // (1,)
        const float* __restrict__ b1,       // (128,)
        const float* __restrict__ b2,       // (64,)
        const float* __restrict__ b3,       // (10,)
        const unsigned* __restrict__ w1t,   // [128][28]
        const unsigned long long* __restrict__ w2b, // [2][64]
        const unsigned long long* __restrict__ w3b, // [10]
        float* __restrict__ out,            // (B,10)
        int B)
{
    const int tid  = threadIdx.x;
    const int lane = tid & 63;
    const int half = lane >> 5;             // row parity
    const int c    = lane & 31;             // column
    const int wid  = __builtin_amdgcn_readfirstlane(tid >> 6);
    const long s   = (long)blockIdx.x * 4 + wid;   // sample, wave-uniform
    if (s >= (long)B) return;                      // wave-uniform exit

    // lane's element for (step t, channel ch) is vb[ch*1024 + t*64]
    const float* __restrict__ vb = x + (size_t)s * 3072 + half * 32 + c;
    const float cb = conv_b[0];

    float buf[8][3];            // 8-row ring: 24 loads in flight (deep MLP)
    float A[6];                 // pending rows at distance d from MY row
    unsigned rowbits = 0;       // lanes 0..27 end holding output row bits

    #pragma unroll
    for (int p = 0; p < 8; ++p) {
        #pragma unroll
        for (int ch = 0; ch < 3; ++ch)
            buf[p][ch] = vb[ch * 1024 + p * 64];
    }
    #pragma unroll
    for (int j = 0; j < 6; ++j) A[j] = 0.0f;

    #pragma unroll
    for (int t = 0; t < 16; ++t) {
        // 15 shifted operands from 3 register values via DPP wave_shr:1
        // (cross-half leakage lands only in cols 28..31 -> masked)
        float v[3][5];
        #pragma unroll
        for (int ch = 0; ch < 3; ++ch) {
            float s0 = buf[t & 7][ch];
            v[ch][0] = s0;
            int iv = __builtin_bit_cast(int, s0);
            #pragma unroll
            for (int k = 1; k <= 4; ++k) {
                iv = __builtin_amdgcn_update_dpp(0, iv, DPP_WAVE_SHR1,
                                                 0xF, 0xF, true);
                v[ch][k] = __builtin_bit_cast(float, iv);
            }
        }
        // refill the ring slot freed this step with row t+8
        if (t + 8 < 16) {
            #pragma unroll
            for (int ch = 0; ch < 3; ++ch)
                buf[t & 7][ch] = vb[ch * 1024 + (t + 8) * 64];
        }
        // accumulate my row (2t+half) into pending rows d=0..4 (kr = d);
        // invalid-orow contributions land in slots retire never reads.
        #pragma unroll
        for (int d = 0; d < 5; ++d) {
            float a = A[d];
            #pragma unroll
            for (int ch = 0; ch < 3; ++ch)
                #pragma unroll
                for (int kc = 0; kc < 5; ++kc)
                    a = fmaf(v[ch][kc], conv_w[ch * 25 + d * 5 + kc], a);
            A[d] = a;
        }
        // retire output rows 2t-4 (h0 A[4] / h1 A[5]) and 2t-3 (A[3]/A[4])
        if (t >= 2) {
            float ra = half ? A[5] : A[4];
            float rb = half ? A[4] : A[3];
            float pa = ra + __shfl_xor(ra, 32) + cb;
            float pb = rb + __shfl_xor(rb, 32) + cb;
            unsigned mba = (unsigned)__ballot(pa != 0.0f) & 0x0FFFFFFFu;
            unsigned mbb = (unsigned)__ballot(pb != 0.0f) & 0x0FFFFFFFu;
            if (lane == 2 * t - 4) rowbits = mba;
            if (lane == 2 * t - 3) rowbits = mbb;
        }
        // rotate distances by 2 (register renames, free under full unroll)
        A[5] = A[3]; A[4] = A[2]; A[3] = A[1]; A[2] = A[0];
        A[1] = 0.0f; A[0] = 0.0f;
    }

    // ---- pack 28x28 row-bits into 25 u32 words (word c on lanes c<25) ----
    unsigned myword;
    {
        const int r0 = (c * 32) / 28;        // sh = 32c-28*r0 in {0,4,...,24}
        const int sh = c * 32 - r0 * 28;
        unsigned rb0 = __shfl(rowbits, r0);
        unsigned rb1 = __shfl(rowbits, r0 + 1);  // lane 28 holds 0
        unsigned long long v = (unsigned long long)rb0
                             | ((unsigned long long)rb1 << 28);
        myword = (c < 25) ? (unsigned)(v >> sh) : 0u;
    }

    // ---- layer 1: lane computes outputs `lane` and `lane+64` ----
    const uint4* wa = (const uint4*)(w1t + (size_t)lane * NW1P);
    const uint4* wb = (const uint4*)(w1t + (size_t)(lane + 64) * NW1P);
    int sa = 0, sb = 0;
    #pragma unroll
    for (int q = 0; q < 7; ++q) {
        uint4 a = wa[q], b = wb[q];
        unsigned x0 = (unsigned)__builtin_amdgcn_readlane((int)myword, q * 4 + 0);
        unsigned x1 = (unsigned)__builtin_amdgcn_readlane((int)myword, q * 4 + 1);
        unsigned x2 = (unsigned)__builtin_amdgcn_readlane((int)myword, q * 4 + 2);
        unsigned x3 = (unsigned)__builtin_amdgcn_readlane((int)myword, q * 4 + 3);
        sa += __popc(x0 ^ a.x) + __popc(x1 ^ a.y)
            + __popc(x2 ^ a.z) + __popc(x3 ^ a.w);
        sb += __popc(x0 ^ b.x) + __popc(x1 ^ b.y)
            + __popc(x2 ^ b.z) + __popc(x3 ^ b.w);
    }
    float preA = (float)sa + b1[lane]      - 392.0f;
    float preB = (float)sb + b1[lane + 64] - 392.0f;
    unsigned long long h1lo = __ballot(preA >= 0.0f);
    unsigned long long h1hi = __ballot(preB >= 0.0f);

    // ---- layer 2 ----
    int s2 = __popcll(h1lo ^ w2b[lane]) + __popcll(h1hi ^ w2b[64 + lane]);
    float pre2 = (float)s2 + b2[lane] - 64.0f;
    unsigned long long h2 = __ballot(pre2 >= 0.0f);

    // ---- layer 3 + log_softmax (lanes 0..9 hold logits) ----
    float logit = -INFINITY;
    if (lane < 10)
        logit = (float)__popcll(h2 ^ w3b[lane]) + b3[lane] - 32.0f;
    float m = logit;
    #pragma unroll
    for (int off = 8; off >= 1; off >>= 1)
        m = fmaxf(m, __shfl_xor(m, off, 16));
    float e = (lane < 10) ? expf(logit - m) : 0.0f;
    float ssum = e;
    #pragma unroll
    for (int off = 8; off >= 1; off >>= 1)
        ssum += __shfl_xor(ssum, off, 16);
    if (lane < 10)
        out[s * 10 + lane] = logit - m - logf(ssum);
}

extern "C" void kernel_launch(void* const* d_in, const int* in_sizes, int n_in,
                              void* d_out, int out_size, void* d_ws, size_t ws_size,
                              hipStream_t stream) {
    const float* x      = (const float*)d_in[0];
    const float* conv_w = (const float*)d_in[1];
    const float* conv_b = (const float*)d_in[2];
    const float* W1     = (const float*)d_in[3];
    const float* b1     = (const float*)d_in[4];
    const float* W2     = (const float*)d_in[5];
    const float* b2     = (const float*)d_in[6];
    const float* W3     = (const float*)d_in[7];
    const float* b3     = (const float*)d_in[8];
    float* out = (float*)d_out;

    const int B = in_sizes[0] / (3 * 32 * 32);

    // workspace layout
    unsigned* w1t            = (unsigned*)d_ws;                            // 14336 B
    unsigned long long* w2b  = (unsigned long long*)((char*)d_ws + 14336); // 1024 B
    unsigned long long* w3b  = (unsigned long long*)((char*)d_ws + 15360); // 80 B

    pack_weights<<<W1_BLOCKS + W2_BLOCKS + 1, 256, 0, stream>>>(
        W1, W2, W3, w1t, w2b, w3b);

    net_all<<<(B + 3) / 4, 256, 0, stream>>>(x, conv_w, conv_b, b1, b2, b3,
                                             w1t, w2b, w3b, out, B);
}

// Round 9
// 41.873 us; speedup vs baseline: 1.1361x; 1.1361x over previous
//
#include <hip/hip_runtime.h>
#include <math.h>

// ---------------------------------------------------------------------------
// Net: conv2d(3->1,5x5,VALID) + bias -> xor_linear(784->128) -> step ->
//      xor_linear(128->64) -> step -> xor_linear(64->10) -> log_softmax
//
// xor_linear(X,W,b) = popcount(Xbits ^ Wbits) + b - in/2. First layer
// binarizes with (conv+bias != 0) [ref: Xb = (X != 0)], later layers with
// step() (>= 0). Integer-exact -> bit-exact thresholds.
//
// Structure: ONE sample per wave (8192 waves). lane = rowparity*32 + col;
// step t processes input rows 2t (lanes 0-31) and 2t+1 (lanes 32-63).
// Column shifts via chained DPP wave_shr:1 (pure VALU). A[d] = pending
// output row at distance d from MY row; rotates by 2/step via static
// renames. Retire: __shfl_xor(.,32) combines halves, ballot binarizes,
// lanes 0..27 collect row masks. Binary tail per-wave.
//
// ROUND-9 CHANGE: __launch_bounds__(256) ONLY. Rounds 5-8 used (256,8)
// => amdgpu-waves-per-eu=8 => 32-VGPR allocator cap => scratch spills
// (r8 counters: VGPR_Count=32, WRITE_SIZE=16.7MB vs 0.33MB output,
// occupancy 4%). Every "optimization" since r5 fought that ceiling.
// Uncapped, the kernel needs ~60 VGPR -> zero spills. Ring shrunk to 4
// rows (12 VGPR): x is L3-resident (FETCH 55MB < 256MB L3), so ~900cy
// lookahead suffices. No LDS, no barriers, no atomics.
// ---------------------------------------------------------------------------

#define NW1P 28   // padded u32 words per W1 row
#define DPP_WAVE_SHR1 0x138
#define W1_BLOCKS 400   // 128 rows * 25 words * 32 bits / 256 threads
#define W2_BLOCKS 32    // 128 u64 words, 4 per block (one ballot per wave)

__global__ void pack_weights(const float* __restrict__ W1,
                             const float* __restrict__ W2,
                             const float* __restrict__ W3,
                             unsigned* __restrict__ w1t,
                             unsigned long long* __restrict__ w2b,
                             unsigned long long* __restrict__ w3b) {
    const int bid = blockIdx.x, t = threadIdx.x;
    const int lane = t & 63, wv = t >> 6;
    if (bid < W1_BLOCKS) {
        // one bit per lane; ballot assembles two u32 words per wave
        int gid = bid * 256 + t;
        int wf  = gid >> 5;                 // flat word index 0..3199
        int bit = gid & 31;
        int i = wf / 25, j = wf - i * 25;   // row i, word j
        int col = j * 32 + bit;
        bool v = (col < 784) && (W1[i * 784 + col] != 0.0f);
        unsigned long long m = __ballot(v);
        if (bit == 0)
            w1t[i * NW1P + j] = (unsigned)(m >> ((t & 32) ? 32 : 0));
    } else if (bid < W1_BLOCKS + W2_BLOCKS) {
        // one u64 word per wave: word f = w*64+i holds W2[i][w*64+lane]
        int f = (bid - W1_BLOCKS) * 4 + wv;       // 0..127
        int w = f >> 6, i = f & 63;
        bool v = W2[i * 128 + w * 64 + lane] != 0.0f;
        unsigned long long m = __ballot(v);
        if (lane == 0) w2b[f] = m;
    } else {
        if (wv == 0) {                             // W3: 10 ballots on wave 0
            #pragma unroll
            for (int f = 0; f < 10; ++f) {
                bool v = W3[f * 64 + lane] != 0.0f;
                unsigned long long m = __ballot(v);
                if (lane == 0) w3b[f] = m;
            }
        } else if (t >= 128 && t < 256) {          // zero w1t pad words
            int i = t - 128;
            w1t[i * NW1P + 25] = 0;
            w1t[i * NW1P + 26] = 0;
            w1t[i * NW1P + 27] = 0;
        }
    }
}

__global__ __launch_bounds__(256) void net_all(
        const float* __restrict__ x,        // (B,3,32,32)
        const float* __restrict__ conv_w,   // (1,3,5,5)
        const float* __restrict__ conv_b,   // (1,)
        const float* __restrict__ b1,       // (128,)
        const float* __restrict__ b2,       // (64,)
        const float* __restrict__ b3,       // (10,)
        const unsigned* __restrict__ w1t,   // [128][28]
        const unsigned long long* __restrict__ w2b, // [2][64]
        const unsigned long long* __restrict__ w3b, // [10]
        float* __restrict__ out,            // (B,10)
        int B)
{
    const int tid  = threadIdx.x;
    const int lane = tid & 63;
    const int half = lane >> 5;             // row parity
    const int c    = lane & 31;             // column
    const int wid  = __builtin_amdgcn_readfirstlane(tid >> 6);
    const long s   = (long)blockIdx.x * 4 + wid;   // sample, wave-uniform
    if (s >= (long)B) return;                      // wave-uniform exit

    // lane's element for (step t, channel ch) is vb[ch*1024 + t*64]
    const float* __restrict__ vb = x + (size_t)s * 3072 + half * 32 + c;
    const float cb = conv_b[0];

    float buf[4][3];            // 4-row ring: 12 loads in flight
    float A[6];                 // pending rows at distance d from MY row
    unsigned rowbits = 0;       // lanes 0..27 end holding output row bits

    #pragma unroll
    for (int p = 0; p < 4; ++p) {
        #pragma unroll
        for (int ch = 0; ch < 3; ++ch)
            buf[p][ch] = vb[ch * 1024 + p * 64];
    }
    #pragma unroll
    for (int j = 0; j < 6; ++j) A[j] = 0.0f;

    #pragma unroll
    for (int t = 0; t < 16; ++t) {
        // 15 shifted operands from 3 register values via DPP wave_shr:1
        // (cross-half leakage lands only in cols 28..31 -> masked)
        float v[3][5];
        #pragma unroll
        for (int ch = 0; ch < 3; ++ch) {
            float s0 = buf[t & 3][ch];
            v[ch][0] = s0;
            int iv = __builtin_bit_cast(int, s0);
            #pragma unroll
            for (int k = 1; k <= 4; ++k) {
                iv = __builtin_amdgcn_update_dpp(0, iv, DPP_WAVE_SHR1,
                                                 0xF, 0xF, true);
                v[ch][k] = __builtin_bit_cast(float, iv);
            }
        }
        // refill the ring slot freed this step with row t+4
        if (t + 4 < 16) {
            #pragma unroll
            for (int ch = 0; ch < 3; ++ch)
                buf[t & 3][ch] = vb[ch * 1024 + (t + 4) * 64];
        }
        // accumulate my row (2t+half) into pending rows d=0..4 (kr = d);
        // invalid-orow contributions land in slots retire never reads.
        #pragma unroll
        for (int d = 0; d < 5; ++d) {
            float a = A[d];
            #pragma unroll
            for (int ch = 0; ch < 3; ++ch)
                #pragma unroll
                for (int kc = 0; kc < 5; ++kc)
                    a = fmaf(v[ch][kc], conv_w[ch * 25 + d * 5 + kc], a);
            A[d] = a;
        }
        // retire output rows 2t-4 (h0 A[4] / h1 A[5]) and 2t-3 (A[3]/A[4])
        if (t >= 2) {
            float ra = half ? A[5] : A[4];
            float rb = half ? A[4] : A[3];
            float pa = ra + __shfl_xor(ra, 32) + cb;
            float pb = rb + __shfl_xor(rb, 32) + cb;
            unsigned mba = (unsigned)__ballot(pa != 0.0f) & 0x0FFFFFFFu;
            unsigned mbb = (unsigned)__ballot(pb != 0.0f) & 0x0FFFFFFFu;
            if (lane == 2 * t - 4) rowbits = mba;
            if (lane == 2 * t - 3) rowbits = mbb;
        }
        // rotate distances by 2 (register renames, free under full unroll)
        A[5] = A[3]; A[4] = A[2]; A[3] = A[1]; A[2] = A[0];
        A[1] = 0.0f; A[0] = 0.0f;
    }

    // ---- pack 28x28 row-bits into 25 u32 words (word c on lanes c<25) ----
    unsigned myword;
    {
        const int r0 = (c * 32) / 28;        // sh = 32c-28*r0 in {0,4,...,24}
        const int sh = c * 32 - r0 * 28;
        unsigned rb0 = __shfl(rowbits, r0);
        unsigned rb1 = __shfl(rowbits, r0 + 1);  // lane 28 holds 0
        unsigned long long v = (unsigned long long)rb0
                             | ((unsigned long long)rb1 << 28);
        myword = (c < 25) ? (unsigned)(v >> sh) : 0u;
    }

    // ---- layer 1: lane computes outputs `lane` and `lane+64` ----
    const uint4* wa = (const uint4*)(w1t + (size_t)lane * NW1P);
    const uint4* wb = (const uint4*)(w1t + (size_t)(lane + 64) * NW1P);
    int sa = 0, sb = 0;
    #pragma unroll
    for (int q = 0; q < 7; ++q) {
        uint4 a = wa[q], b = wb[q];
        unsigned x0 = (unsigned)__builtin_amdgcn_readlane((int)myword, q * 4 + 0);
        unsigned x1 = (unsigned)__builtin_amdgcn_readlane((int)myword, q * 4 + 1);
        unsigned x2 = (unsigned)__builtin_amdgcn_readlane((int)myword, q * 4 + 2);
        unsigned x3 = (unsigned)__builtin_amdgcn_readlane((int)myword, q * 4 + 3);
        sa += __popc(x0 ^ a.x) + __popc(x1 ^ a.y)
            + __popc(x2 ^ a.z) + __popc(x3 ^ a.w);
        sb += __popc(x0 ^ b.x) + __popc(x1 ^ b.y)
            + __popc(x2 ^ b.z) + __popc(x3 ^ b.w);
    }
    float preA = (float)sa + b1[lane]      - 392.0f;
    float preB = (float)sb + b1[lane + 64] - 392.0f;
    unsigned long long h1lo = __ballot(preA >= 0.0f);
    unsigned long long h1hi = __ballot(preB >= 0.0f);

    // ---- layer 2 ----
    int s2 = __popcll(h1lo ^ w2b[lane]) + __popcll(h1hi ^ w2b[64 + lane]);
    float pre2 = (float)s2 + b2[lane] - 64.0f;
    unsigned long long h2 = __ballot(pre2 >= 0.0f);

    // ---- layer 3 + log_softmax (lanes 0..9 hold logits) ----
    float logit = -INFINITY;
    if (lane < 10)
        logit = (float)__popcll(h2 ^ w3b[lane]) + b3[lane] - 32.0f;
    float m = logit;
    #pragma unroll
    for (int off = 8; off >= 1; off >>= 1)
        m = fmaxf(m, __shfl_xor(m, off, 16));
    float e = (lane < 10) ? expf(logit - m) : 0.0f;
    float ssum = e;
    #pragma unroll
    for (int off = 8; off >= 1; off >>= 1)
        ssum += __shfl_xor(ssum, off, 16);
    if (lane < 10)
        out[s * 10 + lane] = logit - m - logf(ssum);
}

extern "C" void kernel_launch(void* const* d_in, const int* in_sizes, int n_in,
                              void* d_out, int out_size, void* d_ws, size_t ws_size,
                              hipStream_t stream) {
    const float* x      = (const float*)d_in[0];
    const float* conv_w = (const float*)d_in[1];
    const float* conv_b = (const float*)d_in[2];
    const float* W1     = (const float*)d_in[3];
    const float* b1     = (const float*)d_in[4];
    const float* W2     = (const float*)d_in[5];
    const float* b2     = (const float*)d_in[6];
    const float* W3     = (const float*)d_in[7];
    const float* b3     = (const float*)d_in[8];
    float* out = (float*)d_out;

    const int B = in_sizes[0] / (3 * 32 * 32);

    // workspace layout
    unsigned* w1t            = (unsigned*)d_ws;                            // 14336 B
    unsigned long long* w2b  = (unsigned long long*)((char*)d_ws + 14336); // 1024 B
    unsigned long long* w3b  = (unsigned long long*)((char*)d_ws + 15360); // 80 B

    pack_weights<<<W1_BLOCKS + W2_BLOCKS + 1, 256, 0, stream>>>(
        W1, W2, W3, w1t, w2b, w3b);

    net_all<<<(B + 3) / 4, 256, 0, stream>>>(x, conv_w, conv_b, b1, b2, b3,
                                             w1t, w2b, w3b, out, B);
}

// Round 10
// 37.148 us; speedup vs baseline: 1.2806x; 1.1272x over previous
//
#include <hip/hip_runtime.h>
#include <math.h>

// ---------------------------------------------------------------------------
// Net: conv2d(3->1,5x5,VALID) + bias -> xor_linear(784->128) -> step ->
//      xor_linear(128->64) -> step -> xor_linear(64->10) -> log_softmax
//
// xor_linear(X,W,b) = popcount(Xbits ^ Wbits) + b - in/2. First layer
// binarizes with (conv+bias != 0) [ref: Xb = (X != 0)], later layers with
// step() (>= 0). Integer-exact -> bit-exact thresholds.
//
// Structure: ONE sample per wave (8192 waves). lane = rowparity*32 + col;
// step t processes input rows 2t (lanes 0-31) and 2t+1 (lanes 32-63).
// Column shifts via chained DPP wave_shr:1 (pure VALU). A[d] = pending
// output row at distance d from MY row; rotates by 2/step via static
// renames. Retire: v_permlane32_swap_b32 (gfx950 VALU cross-half swap —
// no DS pipe, no lgkmcnt) combines halves, ballot binarizes, lanes 0..27
// collect row masks. Binary tail per-wave.
//
// ROUND-10 CHANGE (r8 redone without the VGPR cap): 8-row register ring
// (24 VGPR, truly in registers now) -> ~1650cy load lookahead, covering
// HBM-miss latency even when co-resident waves convoy on the same vmcnt.
// Plus permlane32_swap retire (DS-pipe waits off the critical path) and
// compile-time valid-orow guards (-120 wasted FMA/wave). No LDS, no
// barriers, no atomics, no launch_bounds wave cap.
// ---------------------------------------------------------------------------

#define NW1P 28   // padded u32 words per W1 row
#define DPP_WAVE_SHR1 0x138
#define W1_BLOCKS 400   // 128 rows * 25 words * 32 bits / 256 threads
#define W2_BLOCKS 32    // 128 u64 words, 4 per block (one ballot per wave)

__global__ void pack_weights(const float* __restrict__ W1,
                             const float* __restrict__ W2,
                             const float* __restrict__ W3,
                             unsigned* __restrict__ w1t,
                             unsigned long long* __restrict__ w2b,
                             unsigned long long* __restrict__ w3b) {
    const int bid = blockIdx.x, t = threadIdx.x;
    const int lane = t & 63, wv = t >> 6;
    if (bid < W1_BLOCKS) {
        // one bit per lane; ballot assembles two u32 words per wave
        int gid = bid * 256 + t;
        int wf  = gid >> 5;                 // flat word index 0..3199
        int bit = gid & 31;
        int i = wf / 25, j = wf - i * 25;   // row i, word j
        int col = j * 32 + bit;
        bool v = (col < 784) && (W1[i * 784 + col] != 0.0f);
        unsigned long long m = __ballot(v);
        if (bit == 0)
            w1t[i * NW1P + j] = (unsigned)(m >> ((t & 32) ? 32 : 0));
    } else if (bid < W1_BLOCKS + W2_BLOCKS) {
        // one u64 word per wave: word f = w*64+i holds W2[i][w*64+lane]
        int f = (bid - W1_BLOCKS) * 4 + wv;       // 0..127
        int w = f >> 6, i = f & 63;
        bool v = W2[i * 128 + w * 64 + lane] != 0.0f;
        unsigned long long m = __ballot(v);
        if (lane == 0) w2b[f] = m;
    } else {
        if (wv == 0) {                             // W3: 10 ballots on wave 0
            #pragma unroll
            for (int f = 0; f < 10; ++f) {
                bool v = W3[f * 64 + lane] != 0.0f;
                unsigned long long m = __ballot(v);
                if (lane == 0) w3b[f] = m;
            }
        } else if (t >= 128 && t < 256) {          // zero w1t pad words
            int i = t - 128;
            w1t[i * NW1P + 25] = 0;
            w1t[i * NW1P + 26] = 0;
            w1t[i * NW1P + 27] = 0;
        }
    }
}

// cross-half combine: returns per-lane (x + x_from(lane^32)) as two addends
// via v_permlane32_swap_b32 (pure VALU). a0=[lo,lo], a1=[hi,hi] after swap.
__device__ __forceinline__ float cross_half_sum(float x) {
    int a0 = __builtin_bit_cast(int, x);
    int a1 = __builtin_bit_cast(int, x);
    asm("v_permlane32_swap_b32 %0, %1" : "+v"(a0), "+v"(a1));
    return __builtin_bit_cast(float, a0) + __builtin_bit_cast(float, a1);
}

__global__ __launch_bounds__(256) void net_all(
        const float* __restrict__ x,        // (B,3,32,32)
        const float* __restrict__ conv_w,   // (1,3,5,5)
        const float* __restrict__ conv_b,   // (1,)
        const float* __restrict__ b1,       // (128,)
        const float* __restrict__ b2,       // (64,)
        const float* __restrict__ b3,       // (10,)
        const unsigned* __restrict__ w1t,   // [128][28]
        const unsigned long long* __restrict__ w2b, // [2][64]
        const unsigned long long* __restrict__ w3b, // [10]
        float* __restrict__ out,            // (B,10)
        int B)
{
    const int tid  = threadIdx.x;
    const int lane = tid & 63;
    const int half = lane >> 5;             // row parity
    const int c    = lane & 31;             // column
    const int wid  = __builtin_amdgcn_readfirstlane(tid >> 6);
    const long s   = (long)blockIdx.x * 4 + wid;   // sample, wave-uniform
    if (s >= (long)B) return;                      // wave-uniform exit

    // lane's element for (step t, channel ch) is vb[ch*1024 + t*64]
    const float* __restrict__ vb = x + (size_t)s * 3072 + half * 32 + c;
    const float cb = conv_b[0];

    float buf[8][3];            // 8-row ring: 24 loads in flight (~1650cy)
    float A[6];                 // pending rows at distance d from MY row
    unsigned rowbits = 0;       // lanes 0..27 end holding output row bits

    #pragma unroll
    for (int p = 0; p < 8; ++p) {
        #pragma unroll
        for (int ch = 0; ch < 3; ++ch)
            buf[p][ch] = vb[ch * 1024 + p * 64];
    }
    #pragma unroll
    for (int j = 0; j < 6; ++j) A[j] = 0.0f;

    #pragma unroll
    for (int t = 0; t < 16; ++t) {
        // 15 shifted operands from 3 register values via DPP wave_shr:1
        // (cross-half leakage lands only in cols 28..31 -> masked)
        float v[3][5];
        #pragma unroll
        for (int ch = 0; ch < 3; ++ch) {
            float s0 = buf[t & 7][ch];
            v[ch][0] = s0;
            int iv = __builtin_bit_cast(int, s0);
            #pragma unroll
            for (int k = 1; k <= 4; ++k) {
                iv = __builtin_amdgcn_update_dpp(0, iv, DPP_WAVE_SHR1,
                                                 0xF, 0xF, true);
                v[ch][k] = __builtin_bit_cast(float, iv);
            }
        }
        // refill the ring slot freed this step with row t+8
        if (t + 8 < 16) {
            #pragma unroll
            for (int ch = 0; ch < 3; ++ch)
                buf[t & 7][ch] = vb[ch * 1024 + (t + 8) * 64];
        }
        // accumulate my row (2t+half) into pending rows d=0..4 (kr = d);
        // compile-time guard: skip d where BOTH halves' orows are invalid.
        #pragma unroll
        for (int d = 0; d < 5; ++d) {
            if (2 * t + 1 - d >= 0 && 2 * t - d <= 27) {
                float a = A[d];
                #pragma unroll
                for (int ch = 0; ch < 3; ++ch)
                    #pragma unroll
                    for (int kc = 0; kc < 5; ++kc)
                        a = fmaf(v[ch][kc], conv_w[ch * 25 + d * 5 + kc], a);
                A[d] = a;
            }
        }
        // retire output rows 2t-4 (h0 A[4] / h1 A[5]) and 2t-3 (A[3]/A[4])
        if (t >= 2) {
            float ra = half ? A[5] : A[4];
            float rb = half ? A[4] : A[3];
            float pa = cross_half_sum(ra) + cb;
            float pb = cross_half_sum(rb) + cb;
            unsigned mba = (unsigned)__ballot(pa != 0.0f) & 0x0FFFFFFFu;
            unsigned mbb = (unsigned)__ballot(pb != 0.0f) & 0x0FFFFFFFu;
            if (lane == 2 * t - 4) rowbits = mba;
            if (lane == 2 * t - 3) rowbits = mbb;
        }
        // rotate distances by 2 (register renames, free under full unroll)
        A[5] = A[3]; A[4] = A[2]; A[3] = A[1]; A[2] = A[0];
        A[1] = 0.0f; A[0] = 0.0f;
    }

    // ---- pack 28x28 row-bits into 25 u32 words (word c on lanes c<25) ----
    unsigned myword;
    {
        const int r0 = (c * 32) / 28;        // sh = 32c-28*r0 in {0,4,...,24}
        const int sh = c * 32 - r0 * 28;
        unsigned rb0 = __shfl(rowbits, r0);
        unsigned rb1 = __shfl(rowbits, r0 + 1);  // lane 28 holds 0
        unsigned long long v = (unsigned long long)rb0
                             | ((unsigned long long)rb1 << 28);
        myword = (c < 25) ? (unsigned)(v >> sh) : 0u;
    }

    // ---- layer 1: lane computes outputs `lane` and `lane+64` ----
    const uint4* wa = (const uint4*)(w1t + (size_t)lane * NW1P);
    const uint4* wb = (const uint4*)(w1t + (size_t)(lane + 64) * NW1P);
    int sa = 0, sb = 0;
    #pragma unroll
    for (int q = 0; q < 7; ++q) {
        uint4 a = wa[q], b = wb[q];
        unsigned x0 = (unsigned)__builtin_amdgcn_readlane((int)myword, q * 4 + 0);
        unsigned x1 = (unsigned)__builtin_amdgcn_readlane((int)myword, q * 4 + 1);
        unsigned x2 = (unsigned)__builtin_amdgcn_readlane((int)myword, q * 4 + 2);
        unsigned x3 = (unsigned)__builtin_amdgcn_readlane((int)myword, q * 4 + 3);
        sa += __popc(x0 ^ a.x) + __popc(x1 ^ a.y)
            + __popc(x2 ^ a.z) + __popc(x3 ^ a.w);
        sb += __popc(x0 ^ b.x) + __popc(x1 ^ b.y)
            + __popc(x2 ^ b.z) + __popc(x3 ^ b.w);
    }
    float preA = (float)sa + b1[lane]      - 392.0f;
    float preB = (float)sb + b1[lane + 64] - 392.0f;
    unsigned long long h1lo = __ballot(preA >= 0.0f);
    unsigned long long h1hi = __ballot(preB >= 0.0f);

    // ---- layer 2 ----
    int s2 = __popcll(h1lo ^ w2b[lane]) + __popcll(h1hi ^ w2b[64 + lane]);
    float pre2 = (float)s2 + b2[lane] - 64.0f;
    unsigned long long h2 = __ballot(pre2 >= 0.0f);

    // ---- layer 3 + log_softmax (lanes 0..9 hold logits) ----
    float logit = -INFINITY;
    if (lane < 10)
        logit = (float)__popcll(h2 ^ w3b[lane]) + b3[lane] - 32.0f;
    float m = logit;
    #pragma unroll
    for (int off = 8; off >= 1; off >>= 1)
        m = fmaxf(m, __shfl_xor(m, off, 16));
    float e = (lane < 10) ? expf(logit - m) : 0.0f;
    float ssum = e;
    #pragma unroll
    for (int off = 8; off >= 1; off >>= 1)
        ssum += __shfl_xor(ssum, off, 16);
    if (lane < 10)
        out[s * 10 + lane] = logit - m - logf(ssum);
}

extern "C" void kernel_launch(void* const* d_in, const int* in_sizes, int n_in,
                              void* d_out, int out_size, void* d_ws, size_t ws_size,
                              hipStream_t stream) {
    const float* x      = (const float*)d_in[0];
    const float* conv_w = (const float*)d_in[1];
    const float* conv_b = (const float*)d_in[2];
    const float* W1     = (const float*)d_in[3];
    const float* b1     = (const float*)d_in[4];
    const float* W2     = (const float*)d_in[5];
    const float* b2     = (const float*)d_in[6];
    const float* W3     = (const float*)d_in[7];
    const float* b3     = (const float*)d_in[8];
    float* out = (float*)d_out;

    const int B = in_sizes[0] / (3 * 32 * 32);

    // workspace layout
    unsigned* w1t            = (unsigned*)d_ws;                            // 14336 B
    unsigned long long* w2b  = (unsigned long long*)((char*)d_ws + 14336); // 1024 B
    unsigned long long* w3b  = (unsigned long long*)((char*)d_ws + 15360); // 80 B

    pack_weights<<<W1_BLOCKS + W2_BLOCKS + 1, 256, 0, stream>>>(
        W1, W2, W3, w1t, w2b, w3b);

    net_all<<<(B + 3) / 4, 256, 0, stream>>>(x, conv_w, conv_b, b1, b2, b3,
                                             w1t, w2b, w3b, out, B);
}

// Round 11
// 36.707 us; speedup vs baseline: 1.2960x; 1.0120x over previous
//
#include <hip/hip_runtime.h>
#include <math.h>

// ---------------------------------------------------------------------------
// Net: conv2d(3->1,5x5,VALID) + bias -> xor_linear(784->128) -> step ->
//      xor_linear(128->64) -> step -> xor_linear(64->10) -> log_softmax
//
// xor_linear(X,W,b) = popcount(Xbits ^ Wbits) + b - in/2. First layer
// binarizes with (conv+bias != 0) [ref: Xb = (X != 0)], later layers with
// step() (>= 0). Integer-exact -> bit-exact thresholds.
//
// Structure: ONE sample per wave (8192 waves). lane = rowparity*32 + col;
// step t processes input rows 2t (lanes 0-31) and 2t+1 (lanes 32-63).
// Column shifts via chained DPP wave_shr:1 (pure VALU). A[d] = pending
// output row at distance d from MY row; rotates by 2/step via static
// renames. Retire: v_permlane32_swap_b32 (VALU cross-half swap) combines
// halves, ballot binarizes, lanes 0..27 collect row masks. Binary tail
// per-wave (readlane broadcasts). No LDS, no barriers, no atomics.
//
// ROUND-11 CHANGE: FULL upfront sample load — buf[16][3] = 48 dword loads
// per lane issued in one burst at kernel entry (one latency exposure per
// wave), conv body has ZERO interior vmem. r7/r9/r10 dur-vs-depth slope
// (1.5: ~45us, 4: 41.9, 8: 37.1) showed per-step vmcnt convoy stalls were
// the plateau; this is that axis taken to its endpoint. ~110 VGPR -> 4
// waves/SIMD, which saturates issue when waves never stall internally.
// ---------------------------------------------------------------------------

#define NW1P 28   // padded u32 words per W1 row
#define DPP_WAVE_SHR1 0x138
#define W1_BLOCKS 400   // 128 rows * 25 words * 32 bits / 256 threads
#define W2_BLOCKS 32    // 128 u64 words, 4 per block (one ballot per wave)

__global__ void pack_weights(const float* __restrict__ W1,
                             const float* __restrict__ W2,
                             const float* __restrict__ W3,
                             unsigned* __restrict__ w1t,
                             unsigned long long* __restrict__ w2b,
                             unsigned long long* __restrict__ w3b) {
    const int bid = blockIdx.x, t = threadIdx.x;
    const int lane = t & 63, wv = t >> 6;
    if (bid < W1_BLOCKS) {
        // one bit per lane; ballot assembles two u32 words per wave
        int gid = bid * 256 + t;
        int wf  = gid >> 5;                 // flat word index 0..3199
        int bit = gid & 31;
        int i = wf / 25, j = wf - i * 25;   // row i, word j
        int col = j * 32 + bit;
        bool v = (col < 784) && (W1[i * 784 + col] != 0.0f);
        unsigned long long m = __ballot(v);
        if (bit == 0)
            w1t[i * NW1P + j] = (unsigned)(m >> ((t & 32) ? 32 : 0));
    } else if (bid < W1_BLOCKS + W2_BLOCKS) {
        // one u64 word per wave: word f = w*64+i holds W2[i][w*64+lane]
        int f = (bid - W1_BLOCKS) * 4 + wv;       // 0..127
        int w = f >> 6, i = f & 63;
        bool v = W2[i * 128 + w * 64 + lane] != 0.0f;
        unsigned long long m = __ballot(v);
        if (lane == 0) w2b[f] = m;
    } else {
        if (wv == 0) {                             // W3: 10 ballots on wave 0
            #pragma unroll
            for (int f = 0; f < 10; ++f) {
                bool v = W3[f * 64 + lane] != 0.0f;
                unsigned long long m = __ballot(v);
                if (lane == 0) w3b[f] = m;
            }
        } else if (t >= 128 && t < 256) {          // zero w1t pad words
            int i = t - 128;
            w1t[i * NW1P + 25] = 0;
            w1t[i * NW1P + 26] = 0;
            w1t[i * NW1P + 27] = 0;
        }
    }
}

// cross-half combine via v_permlane32_swap_b32 (pure VALU, no DS pipe):
// returns x + x_from(lane^32).
__device__ __forceinline__ float cross_half_sum(float x) {
    int a0 = __builtin_bit_cast(int, x);
    int a1 = __builtin_bit_cast(int, x);
    asm("v_permlane32_swap_b32 %0, %1" : "+v"(a0), "+v"(a1));
    return __builtin_bit_cast(float, a0) + __builtin_bit_cast(float, a1);
}

__global__ __launch_bounds__(256) void net_all(
        const float* __restrict__ x,        // (B,3,32,32)
        const float* __restrict__ conv_w,   // (1,3,5,5)
        const float* __restrict__ conv_b,   // (1,)
        const float* __restrict__ b1,       // (128,)
        const float* __restrict__ b2,       // (64,)
        const float* __restrict__ b3,       // (10,)
        const unsigned* __restrict__ w1t,   // [128][28]
        const unsigned long long* __restrict__ w2b, // [2][64]
        const unsigned long long* __restrict__ w3b, // [10]
        float* __restrict__ out,            // (B,10)
        int B)
{
    const int tid  = threadIdx.x;
    const int lane = tid & 63;
    const int half = lane >> 5;             // row parity
    const int c    = lane & 31;             // column
    const int wid  = __builtin_amdgcn_readfirstlane(tid >> 6);
    const long s   = (long)blockIdx.x * 4 + wid;   // sample, wave-uniform
    if (s >= (long)B) return;                      // wave-uniform exit

    // lane's element for (step t, channel ch) is vb[ch*1024 + t*64]
    const float* __restrict__ vb = x + (size_t)s * 3072 + half * 32 + c;
    const float cb = conv_b[0];

    // ---- FULL upfront load: 48 dwords/lane, one latency exposure ----
    float buf[16][3];
    #pragma unroll
    for (int p = 0; p < 16; ++p) {
        #pragma unroll
        for (int ch = 0; ch < 3; ++ch)
            buf[p][ch] = vb[ch * 1024 + p * 64];
    }

    float A[6];                 // pending rows at distance d from MY row
    unsigned rowbits = 0;       // lanes 0..27 end holding output row bits
    #pragma unroll
    for (int j = 0; j < 6; ++j) A[j] = 0.0f;

    #pragma unroll
    for (int t = 0; t < 16; ++t) {
        // 15 shifted operands from 3 register values via DPP wave_shr:1
        // (cross-half leakage lands only in cols 28..31 -> masked)
        float v[3][5];
        #pragma unroll
        for (int ch = 0; ch < 3; ++ch) {
            float s0 = buf[t][ch];
            v[ch][0] = s0;
            int iv = __builtin_bit_cast(int, s0);
            #pragma unroll
            for (int k = 1; k <= 4; ++k) {
                iv = __builtin_amdgcn_update_dpp(0, iv, DPP_WAVE_SHR1,
                                                 0xF, 0xF, true);
                v[ch][k] = __builtin_bit_cast(float, iv);
            }
        }
        // accumulate my row (2t+half) into pending rows d=0..4 (kr = d);
        // compile-time guard: skip d where BOTH halves' orows are invalid.
        #pragma unroll
        for (int d = 0; d < 5; ++d) {
            if (2 * t + 1 - d >= 0 && 2 * t - d <= 27) {
                float a = A[d];
                #pragma unroll
                for (int ch = 0; ch < 3; ++ch)
                    #pragma unroll
                    for (int kc = 0; kc < 5; ++kc)
                        a = fmaf(v[ch][kc], conv_w[ch * 25 + d * 5 + kc], a);
                A[d] = a;
            }
        }
        // retire output rows 2t-4 (h0 A[4] / h1 A[5]) and 2t-3 (A[3]/A[4])
        if (t >= 2) {
            float ra = half ? A[5] : A[4];
            float rb = half ? A[4] : A[3];
            float pa = cross_half_sum(ra) + cb;
            float pb = cross_half_sum(rb) + cb;
            unsigned mba = (unsigned)__ballot(pa != 0.0f) & 0x0FFFFFFFu;
            unsigned mbb = (unsigned)__ballot(pb != 0.0f) & 0x0FFFFFFFu;
            if (lane == 2 * t - 4) rowbits = mba;
            if (lane == 2 * t - 3) rowbits = mbb;
        }
        // rotate distances by 2 (register renames, free under full unroll)
        A[5] = A[3]; A[4] = A[2]; A[3] = A[1]; A[2] = A[0];
        A[1] = 0.0f; A[0] = 0.0f;
    }

    // ---- pack 28x28 row-bits into 25 u32 words (word c on lanes c<25) ----
    unsigned myword;
    {
        const int r0 = (c * 32) / 28;        // sh = 32c-28*r0 in {0,4,...,24}
        const int sh = c * 32 - r0 * 28;
        unsigned rb0 = __shfl(rowbits, r0);
        unsigned rb1 = __shfl(rowbits, r0 + 1);  // lane 28 holds 0
        unsigned long long v = (unsigned long long)rb0
                             | ((unsigned long long)rb1 << 28);
        myword = (c < 25) ? (unsigned)(v >> sh) : 0u;
    }

    // ---- layer 1: lane computes outputs `lane` and `lane+64` ----
    const uint4* wa = (const uint4*)(w1t + (size_t)lane * NW1P);
    const uint4* wb = (const uint4*)(w1t + (size_t)(lane + 64) * NW1P);
    int sa = 0, sb = 0;
    #pragma unroll
    for (int q = 0; q < 7; ++q) {
        uint4 a = wa[q], b = wb[q];
        unsigned x0 = (unsigned)__builtin_amdgcn_readlane((int)myword, q * 4 + 0);
        unsigned x1 = (unsigned)__builtin_amdgcn_readlane((int)myword, q * 4 + 1);
        unsigned x2 = (unsigned)__builtin_amdgcn_readlane((int)myword, q * 4 + 2);
        unsigned x3 = (unsigned)__builtin_amdgcn_readlane((int)myword, q * 4 + 3);
        sa += __popc(x0 ^ a.x) + __popc(x1 ^ a.y)
            + __popc(x2 ^ a.z) + __popc(x3 ^ a.w);
        sb += __popc(x0 ^ b.x) + __popc(x1 ^ b.y)
            + __popc(x2 ^ b.z) + __popc(x3 ^ b.w);
    }
    float preA = (float)sa + b1[lane]      - 392.0f;
    float preB = (float)sb + b1[lane + 64] - 392.0f;
    unsigned long long h1lo = __ballot(preA >= 0.0f);
    unsigned long long h1hi = __ballot(preB >= 0.0f);

    // ---- layer 2 ----
    int s2 = __popcll(h1lo ^ w2b[lane]) + __popcll(h1hi ^ w2b[64 + lane]);
    float pre2 = (float)s2 + b2[lane] - 64.0f;
    unsigned long long h2 = __ballot(pre2 >= 0.0f);

    // ---- layer 3 + log_softmax (lanes 0..9 hold logits) ----
    float logit = -INFINITY;
    if (lane < 10)
        logit = (float)__popcll(h2 ^ w3b[lane]) + b3[lane] - 32.0f;
    float m = logit;
    #pragma unroll
    for (int off = 8; off >= 1; off >>= 1)
        m = fmaxf(m, __shfl_xor(m, off, 16));
    float e = (lane < 10) ? expf(logit - m) : 0.0f;
    float ssum = e;
    #pragma unroll
    for (int off = 8; off >= 1; off >>= 1)
        ssum += __shfl_xor(ssum, off, 16);
    if (lane < 10)
        out[s * 10 + lane] = logit - m - logf(ssum);
}

extern "C" void kernel_launch(void* const* d_in, const int* in_sizes, int n_in,
                              void* d_out, int out_size, void* d_ws, size_t ws_size,
                              hipStream_t stream) {
    const float* x      = (const float*)d_in[0];
    const float* conv_w = (const float*)d_in[1];
    const float* conv_b = (const float*)d_in[2];
    const float* W1     = (const float*)d_in[3];
    const float* b1     = (const float*)d_in[4];
    const float* W2     = (const float*)d_in[5];
    const float* b2     = (const float*)d_in[6];
    const float* W3     = (const float*)d_in[7];
    const float* b3     = (const float*)d_in[8];
    float* out = (float*)d_out;

    const int B = in_sizes[0] / (3 * 32 * 32);

    // workspace layout
    unsigned* w1t            = (unsigned*)d_ws;                            // 14336 B
    unsigned long long* w2b  = (unsigned long long*)((char*)d_ws + 14336); // 1024 B
    unsigned long long* w3b  = (unsigned long long*)((char*)d_ws + 15360); // 80 B

    pack_weights<<<W1_BLOCKS + W2_BLOCKS + 1, 256, 0, stream>>>(
        W1, W2, W3, w1t, w2b, w3b);

    net_all<<<(B + 3) / 4, 256, 0, stream>>>(x, conv_w, conv_b, b1, b2, b3,
                                             w1t, w2b, w3b, out, B);
}